// Round 2
// baseline (1784.398 us; speedup 1.0000x reference)
//
#include <hip/hip_runtime.h>
#include <hip/hip_bf16.h>

// out = A @ b, A sparse COO (rows, cols, vals), N=50000, E=1.6M, D=128, fp32.
// Round 2: coarse bucket sort (32 rows/bucket) + LDS fp32 accumulation.
//   K1 hist_coarse : per-bucket edge counts (atomic)
//   K2 scan        : exclusive scan over NB~1563 buckets (cheap)
//   K3 scatter     : edges -> bucket regions, packed (localrow|col, val)
//   K4 reduce      : 1 block/bucket, 16KB LDS acc, 8 b-row loads in flight,
//                    ds_add_f32 accumulation, coalesced float4 writeout.

#define D_DIM  128
#define R_LOG  5
#define R_ROWS 32   // rows per bucket; localrow fits in 16 bits, col < 65536

// ---------------- coarse histogram ----------------
__global__ __launch_bounds__(256) void hist_coarse(const int* __restrict__ rows,
                                                   int* __restrict__ hist, int E) {
    int e = blockIdx.x * 256 + threadIdx.x;
    if (e < E) atomicAdd(&hist[rows[e] >> R_LOG], 1);
}

// ---------------- exclusive scan (single block, n ~ 1563) ----------------
__global__ __launch_bounds__(1024) void scan_kernel(const int* __restrict__ hist,
                                                    int* __restrict__ bstart,
                                                    int* __restrict__ cursor, int n,
                                                    int total) {
    __shared__ int wsum[16];
    __shared__ int carry_s;
    const int tid  = threadIdx.x;
    const int lane = tid & 63;
    const int wid  = tid >> 6;
    if (tid == 0) carry_s = 0;
    __syncthreads();
    for (int base = 0; base < n; base += 1024) {
        int i = base + tid;
        int v = (i < n) ? hist[i] : 0;
        int x = v;
        #pragma unroll
        for (int off = 1; off < 64; off <<= 1) {
            int y = __shfl_up(x, off, 64);
            if (lane >= off) x += y;
        }
        if (lane == 63) wsum[wid] = x;
        __syncthreads();
        int wpre = 0;
        for (int w = 0; w < wid; ++w) wpre += wsum[w];
        int excl = carry_s + wpre + x - v;
        if (i < n) { bstart[i] = excl; cursor[i] = excl; }
        __syncthreads();
        if (tid == 1023) carry_s = carry_s + wpre + x;
        __syncthreads();
    }
    if (tid == 0) bstart[n] = total;
}

// ---------------- scatter into bucket regions ----------------
__global__ __launch_bounds__(256) void scatter_coarse(const int* __restrict__ rows,
                                                      const int* __restrict__ cols,
                                                      const float* __restrict__ vals,
                                                      int* __restrict__ cursor,
                                                      int2* __restrict__ ebuf, int E) {
    int e = blockIdx.x * 256 + threadIdx.x;
    if (e >= E) return;
    int r = rows[e];
    int bk = r >> R_LOG;
    int pos = atomicAdd(&cursor[bk], 1);
    int rc = ((r & (R_ROWS - 1)) << 16) | cols[e];
    ebuf[pos] = make_int2(rc, __float_as_int(vals[e]));
}

// ---------------- reduce: 1 block per bucket, LDS accumulators ----------------
__global__ __launch_bounds__(256) void reduce_kernel(const int* __restrict__ bstart,
                                                     const int2* __restrict__ ebuf,
                                                     const float* __restrict__ b,
                                                     float* __restrict__ out, int n) {
    __shared__ float acc[R_ROWS * D_DIM];  // 16 KB
    const int tid  = threadIdx.x;
    const int lane = tid & 63;
    const int wid  = tid >> 6;

    #pragma unroll
    for (int i = tid; i < R_ROWS * D_DIM / 4; i += 256)
        reinterpret_cast<float4*>(acc)[i] = make_float4(0.f, 0.f, 0.f, 0.f);
    __syncthreads();

    const int bk = blockIdx.x;
    const int s  = __builtin_amdgcn_readfirstlane(bstart[bk]);
    const int e  = __builtin_amdgcn_readfirstlane(bstart[bk + 1]);

    for (int base = s + wid * 64; base < e; base += 256) {
        int cnt = e - base; if (cnt > 64) cnt = 64;
        int2 cv = make_int2(0, 0);
        if (lane < cnt) cv = ebuf[base + lane];
        if (cnt == 64) {
            #pragma unroll
            for (int j0 = 0; j0 < 64; j0 += 8) {
                float2 bv[8]; int lr[8]; float vv[8];
                #pragma unroll
                for (int k = 0; k < 8; ++k) {
                    int rc  = __shfl(cv.x, j0 + k, 64);
                    vv[k]   = __int_as_float(__shfl(cv.y, j0 + k, 64));
                    lr[k]   = rc >> 16;
                    int col = rc & 0xffff;
                    bv[k]   = *reinterpret_cast<const float2*>(
                                  b + (size_t)col * D_DIM + lane * 2);
                }
                #pragma unroll
                for (int k = 0; k < 8; ++k) {
                    atomicAdd(&acc[lr[k] * D_DIM + lane * 2],     vv[k] * bv[k].x);
                    atomicAdd(&acc[lr[k] * D_DIM + lane * 2 + 1], vv[k] * bv[k].y);
                }
            }
        } else {
            for (int j = 0; j < cnt; ++j) {
                int rc    = __shfl(cv.x, j, 64);
                float val = __int_as_float(__shfl(cv.y, j, 64));
                int lr    = rc >> 16;
                int col   = rc & 0xffff;
                float2 bv = *reinterpret_cast<const float2*>(
                                b + (size_t)col * D_DIM + lane * 2);
                atomicAdd(&acc[lr * D_DIM + lane * 2],     val * bv.x);
                atomicAdd(&acc[lr * D_DIM + lane * 2 + 1], val * bv.y);
            }
        }
    }
    __syncthreads();

    const int row0 = bk << R_LOG;
    #pragma unroll
    for (int i = tid; i < R_ROWS * D_DIM / 4; i += 256) {
        int r   = i >> 5;            // 32 float4 per row
        int row = row0 + r;
        if (row < n)
            *reinterpret_cast<float4*>(out + (size_t)row * D_DIM + (i & 31) * 4) =
                reinterpret_cast<const float4*>(acc)[i];
    }
}

// ---------------- fallback: pure atomic path (if ws too small) ----------------
__global__ __launch_bounds__(256) void zero_kernel(float* __restrict__ out, size_t n4) {
    size_t i = (size_t)blockIdx.x * 256 + threadIdx.x;
    size_t stride = (size_t)gridDim.x * 256;
    for (; i < n4; i += stride)
        reinterpret_cast<float4*>(out)[i] = make_float4(0.f, 0.f, 0.f, 0.f);
}

__global__ __launch_bounds__(256) void atomic_spmm_kernel(const int* __restrict__ rows,
                                                          const int* __restrict__ cols,
                                                          const float* __restrict__ vals,
                                                          const float* __restrict__ b,
                                                          float* __restrict__ out, int E) {
    long long t = (long long)blockIdx.x * 256 + threadIdx.x;
    int e = (int)(t >> 5);
    int q = (int)(t & 31);
    if (e >= E) return;
    int   r = rows[e];
    int   c = cols[e];
    float v = vals[e];
    float4 bb = *reinterpret_cast<const float4*>(b + (size_t)c * D_DIM + q * 4);
    float* o = out + (size_t)r * D_DIM + q * 4;
    atomicAdd(o + 0, v * bb.x);
    atomicAdd(o + 1, v * bb.y);
    atomicAdd(o + 2, v * bb.z);
    atomicAdd(o + 3, v * bb.w);
}

extern "C" void kernel_launch(void* const* d_in, const int* in_sizes, int n_in,
                              void* d_out, int out_size, void* d_ws, size_t ws_size,
                              hipStream_t stream) {
    const int*   idx  = (const int*)d_in[0];   // [2, E] flat int32
    const float* vals = (const float*)d_in[1]; // [E]
    const float* b    = (const float*)d_in[3]; // [N, 128]
    float*       out  = (float*)d_out;

    const int E = in_sizes[1];
    const int N = in_sizes[3] / D_DIM;
    const int* rows = idx;
    const int* cols = idx + E;
    const int NB = (N + R_ROWS - 1) >> R_LOG;

    // ws layout: bstart[NB+1] | hist[NB] | cursor[NB] | ebuf[E] (int2)
    size_t int_bytes = (size_t)(3 * NB + 1) * sizeof(int);
    size_t ebuf_off  = (int_bytes + 7) & ~(size_t)7;
    size_t need      = ebuf_off + (size_t)E * sizeof(int2);

    if (ws_size >= need) {
        char* ws      = (char*)d_ws;
        int*  bstart  = (int*)ws;
        int*  hist    = bstart + (NB + 1);
        int*  cursor  = hist + NB;
        int2* ebuf    = (int2*)(ws + ebuf_off);

        hipMemsetAsync(hist, 0, (size_t)NB * sizeof(int), stream);

        int eb = (E + 255) / 256;
        hist_coarse<<<eb, 256, 0, stream>>>(rows, hist, E);
        scan_kernel<<<1, 1024, 0, stream>>>(hist, bstart, cursor, NB, E);
        scatter_coarse<<<eb, 256, 0, stream>>>(rows, cols, vals, cursor, ebuf, E);
        reduce_kernel<<<NB, 256, 0, stream>>>(bstart, ebuf, b, out, N);
    } else {
        size_t n4 = (size_t)N * D_DIM / 4;
        zero_kernel<<<2048, 256, 0, stream>>>(out, n4);
        long long total = (long long)E * 32;
        int ab = (int)((total + 255) / 256);
        atomic_spmm_kernel<<<ab, 256, 0, stream>>>(rows, cols, vals, b, out, E);
    }
}

// Round 4
// 336.932 us; speedup vs baseline: 5.2960x; 5.2960x over previous
//
#include <hip/hip_runtime.h>
#include <hip/hip_bf16.h>

// out = A @ b, A sparse COO (rows, cols, vals), N=50000, E=1.6M, D=128, fp32.
// Round 3 (resubmit after infra timeout): per-row CSR build (hist ->
// multiblock scan -> XCD-sliced scatter), then one wave per row, register
// float2 accumulation, uniform edge loads (no shfl/bpermute, no LDS atomics),
// 8-deep unrolled gather.

#define D_DIM 128

// ---------------- histogram ----------------
__global__ __launch_bounds__(256) void hist_kernel(const int* __restrict__ rows,
                                                   int* __restrict__ hist, int E) {
    int e = blockIdx.x * 256 + threadIdx.x;
    if (e < E) atomicAdd(&hist[rows[e]], 1);
}

// ---------------- multi-block exclusive scan ----------------
__device__ inline int block_scan_incl(int v, int* wsum) {
    const int lane = threadIdx.x & 63;
    const int wid  = threadIdx.x >> 6;
    int x = v;
    #pragma unroll
    for (int off = 1; off < 64; off <<= 1) {
        int y = __shfl_up(x, off, 64);
        if (lane >= off) x += y;
    }
    if (lane == 63) wsum[wid] = x;
    __syncthreads();
    int wpre = 0;
    for (int w = 0; w < wid; ++w) wpre += wsum[w];
    return wpre + x;  // block-wide inclusive scan of v
}

__global__ __launch_bounds__(1024) void scan1_kernel(const int* __restrict__ hist,
                                                     int* __restrict__ bsum, int n) {
    __shared__ int wsum[16];
    int i = blockIdx.x * 1024 + threadIdx.x;
    int v = (i < n) ? hist[i] : 0;
    int incl = block_scan_incl(v, wsum);
    if (threadIdx.x == 1023) bsum[blockIdx.x] = incl;
}

__global__ __launch_bounds__(64) void scan2_kernel(int* __restrict__ bsum, int nblk,
                                                   int* __restrict__ row_start,
                                                   int n, int total) {
    const int t = threadIdx.x;
    int v = (t < nblk) ? bsum[t] : 0;
    int x = v;
    #pragma unroll
    for (int off = 1; off < 64; off <<= 1) {
        int y = __shfl_up(x, off, 64);
        if (t >= off) x += y;
    }
    if (t < nblk) bsum[t] = x - v;  // exclusive
    if (t == 0) row_start[n] = total;
}

__global__ __launch_bounds__(1024) void scan3_kernel(const int* __restrict__ hist,
                                                     const int* __restrict__ bsum,
                                                     int* __restrict__ row_start,
                                                     int* __restrict__ cursor, int n) {
    __shared__ int wsum[16];
    int i = blockIdx.x * 1024 + threadIdx.x;
    int v = (i < n) ? hist[i] : 0;
    int incl = block_scan_incl(v, wsum);
    int excl = bsum[blockIdx.x] + incl - v;
    if (i < n) { row_start[i] = excl; cursor[i] = excl; }
}

// ---------------- XCD-sliced scatter into per-row CSR ----------------
// 8 blocks cover each 256-edge chunk; block (bid&7) writes only rows whose
// 32-row bucket hashes to that slice. With round-robin bid->XCD mapping the
// 8KB bucket regions in ebuf are each written by a single XCD's L2.
__global__ __launch_bounds__(256) void scatter_sliced(const int* __restrict__ rows,
                                                      const int* __restrict__ cols,
                                                      const float* __restrict__ vals,
                                                      int* __restrict__ cursor,
                                                      int2* __restrict__ ebuf, int E) {
    int chunk = blockIdx.x >> 3;
    int slice = blockIdx.x & 7;
    int e = chunk * 256 + threadIdx.x;
    if (e >= E) return;
    int r = rows[e];
    if (((r >> 5) & 7) != slice) return;
    int pos = atomicAdd(&cursor[r], 1);
    ebuf[pos] = make_int2(cols[e], __float_as_int(vals[e]));
}

// ---------------- reduce: one wave per row, register accumulation ----------------
__global__ __launch_bounds__(256) void reduce_kernel(const int* __restrict__ row_start,
                                                     const int2* __restrict__ ebuf,
                                                     const float* __restrict__ b,
                                                     float* __restrict__ out, int n) {
    const int lane = threadIdx.x & 63;
    const int row  = blockIdx.x * 4 + (threadIdx.x >> 6);
    if (row >= n) return;
    const int s = __builtin_amdgcn_readfirstlane(row_start[row]);
    const int e = __builtin_amdgcn_readfirstlane(row_start[row + 1]);

    const float* bl = b + lane * 2;
    float2 acc = make_float2(0.f, 0.f);

    int j = s;
    for (; j + 8 <= e; j += 8) {
        int2 cv[8];
        #pragma unroll
        for (int k = 0; k < 8; ++k) cv[k] = ebuf[j + k];   // uniform addr: scalar loads
        float2 bv[8];
        #pragma unroll
        for (int k = 0; k < 8; ++k)
            bv[k] = *reinterpret_cast<const float2*>(bl + (size_t)cv[k].x * D_DIM);
        #pragma unroll
        for (int k = 0; k < 8; ++k) {
            float v = __int_as_float(cv[k].y);
            acc.x = fmaf(v, bv[k].x, acc.x);
            acc.y = fmaf(v, bv[k].y, acc.y);
        }
    }
    for (; j < e; ++j) {
        int2 cv = ebuf[j];
        float2 bv = *reinterpret_cast<const float2*>(bl + (size_t)cv.x * D_DIM);
        float v = __int_as_float(cv.y);
        acc.x = fmaf(v, bv.x, acc.x);
        acc.y = fmaf(v, bv.y, acc.y);
    }
    *reinterpret_cast<float2*>(out + (size_t)row * D_DIM + lane * 2) = acc;
}

// ---------------- fallback: pure atomic path (if ws too small) ----------------
__global__ __launch_bounds__(256) void zero_kernel(float* __restrict__ out, size_t n4) {
    size_t i = (size_t)blockIdx.x * 256 + threadIdx.x;
    size_t stride = (size_t)gridDim.x * 256;
    for (; i < n4; i += stride)
        reinterpret_cast<float4*>(out)[i] = make_float4(0.f, 0.f, 0.f, 0.f);
}

__global__ __launch_bounds__(256) void atomic_spmm_kernel(const int* __restrict__ rows,
                                                          const int* __restrict__ cols,
                                                          const float* __restrict__ vals,
                                                          const float* __restrict__ b,
                                                          float* __restrict__ out, int E) {
    long long t = (long long)blockIdx.x * 256 + threadIdx.x;
    int e = (int)(t >> 5);
    int q = (int)(t & 31);
    if (e >= E) return;
    int   r = rows[e];
    int   c = cols[e];
    float v = vals[e];
    float4 bb = *reinterpret_cast<const float4*>(b + (size_t)c * D_DIM + q * 4);
    float* o = out + (size_t)r * D_DIM + q * 4;
    atomicAdd(o + 0, v * bb.x);
    atomicAdd(o + 1, v * bb.y);
    atomicAdd(o + 2, v * bb.z);
    atomicAdd(o + 3, v * bb.w);
}

extern "C" void kernel_launch(void* const* d_in, const int* in_sizes, int n_in,
                              void* d_out, int out_size, void* d_ws, size_t ws_size,
                              hipStream_t stream) {
    const int*   idx  = (const int*)d_in[0];   // [2, E] flat int32
    const float* vals = (const float*)d_in[1]; // [E]
    const float* b    = (const float*)d_in[3]; // [N, 128]
    float*       out  = (float*)d_out;

    const int E = in_sizes[1];
    const int N = in_sizes[3] / D_DIM;
    const int* rows = idx;
    const int* cols = idx + E;
    const int NBLK = (N + 1023) / 1024;  // scan blocks (<= 64)

    // ws layout: row_start[N+1] | hist[N] | cursor[N] | bsum[64] | ebuf[E] (int2)
    size_t int_cnt   = (size_t)(3 * N + 1 + 64);
    size_t ebuf_off  = (int_cnt * sizeof(int) + 7) & ~(size_t)7;
    size_t need      = ebuf_off + (size_t)E * sizeof(int2);

    if (ws_size >= need && NBLK <= 64) {
        char* ws        = (char*)d_ws;
        int*  row_start = (int*)ws;
        int*  hist      = row_start + (N + 1);
        int*  cursor    = hist + N;
        int*  bsum      = cursor + N;
        int2* ebuf      = (int2*)(ws + ebuf_off);

        hipMemsetAsync(hist, 0, (size_t)N * sizeof(int), stream);

        int eb = (E + 255) / 256;
        hist_kernel<<<eb, 256, 0, stream>>>(rows, hist, E);
        scan1_kernel<<<NBLK, 1024, 0, stream>>>(hist, bsum, N);
        scan2_kernel<<<1, 64, 0, stream>>>(bsum, NBLK, row_start, N, E);
        scan3_kernel<<<NBLK, 1024, 0, stream>>>(hist, bsum, row_start, cursor, N);
        scatter_sliced<<<eb * 8, 256, 0, stream>>>(rows, cols, vals, cursor, ebuf, E);
        int rb = (N + 3) / 4;
        reduce_kernel<<<rb, 256, 0, stream>>>(row_start, ebuf, b, out, N);
    } else {
        size_t n4 = (size_t)N * D_DIM / 4;
        zero_kernel<<<2048, 256, 0, stream>>>(out, n4);
        long long total = (long long)E * 32;
        int ab = (int)((total + 255) / 256);
        atomic_spmm_kernel<<<ab, 256, 0, stream>>>(rows, cols, vals, b, out, E);
    }
}